// Round 6
// baseline (3289.554 us; speedup 1.0000x reference)
//
#include <hip/hip_runtime.h>
#include <hip/hip_bf16.h>

#define B_ 64
#define S_ 512
#define D_ 256
#define H_ 512

typedef __attribute__((ext_vector_type(8))) short bf16x8;
typedef __attribute__((ext_vector_type(4))) float f32x4;
typedef __attribute__((ext_vector_type(4))) unsigned int uint4v;
typedef unsigned short ushort_t;

__device__ __forceinline__ ushort_t f2bf(float f) {
    __hip_bfloat16 h = __float2bfloat16(f);   // RNE rounding
    return *reinterpret_cast<ushort_t*>(&h);
}
__device__ __forceinline__ float sigmoid_f(float x) { return 1.f / (1.f + __expf(-x)); }
__device__ __forceinline__ float tanh_f(float x) { return 1.f - 2.f / (__expf(2.f * x) + 1.f); }

// grid: 128 blocks x 64 threads — ONE WAVE PER BLOCK, fully autonomous.
// group g = blockIdx>>5 (batch rows g*16..+15); producer p = blockIdx&31 (h-cols p*16..+15).
// Each wave owns ALL 4 gates for its 16 columns: weight B-frags = 4*(16+8) bf16x8
// = 384 regs/lane in the unified VGPR/AGPR file (1 wave/SIMD). Gate activations and
// c/h state updates happen in-registers in MFMA C-layout (no LDS, no __syncthreads
// anywhere in the loop). h exchange: write-through ushort stores (sc0 sc1) + per-wave
// flag released by in-asm vmcnt(0)+store; consumers poll 32 flags via 64-lane ballot
// and load h A-frags straight from L3 (sc0 sc1 dwordx4).
__global__ __launch_bounds__(64, 1) void lstm_rec(
    const float* __restrict__ X,
    const float* __restrict__ Wf, const float* __restrict__ Wi,
    const float* __restrict__ Wo, const float* __restrict__ Wc,
    const float* __restrict__ bfp, const float* __restrict__ bip,
    const float* __restrict__ bop, const float* __restrict__ bcp,
    const float* __restrict__ Uf, const float* __restrict__ Ui,
    const float* __restrict__ Uo, const float* __restrict__ Uc,
    const float* __restrict__ Wfc,
    float* __restrict__ pred, ushort_t* __restrict__ hbufS,
    unsigned int* __restrict__ flags,
    float* __restrict__ outH, float* __restrict__ outC)
{
    const int lane = threadIdx.x;
    const int q    = lane >> 4;      // MFMA quad
    const int m    = lane & 15;      // A-row / B-col lane index
    const int g    = blockIdx.x >> 5;
    const int p    = blockIdx.x & 31;
    const int base = p * 16;         // this wave's h-column range [base, base+16)

    const float* Us[4] = {Uf, Ui, Uo, Uc};
    const float* Ws[4] = {Wf, Wi, Wo, Wc};
    const float* bs[4] = {bfp, bip, bop, bcp};

    // ---- one-time: all 4 gates' B-fragments for our 16 cols (fp32 -> bf16 RNE) ----
    // B-frag (16x16x32): lane holds col n = base+m, k = ks*32 + q*8 + j
    bf16x8 UF[4][16];
    bf16x8 WF[4][8];
    float  bias[4];
    #pragma unroll
    for (int g4 = 0; g4 < 4; ++g4) {
        bias[g4] = bs[g4][base + m];
        #pragma unroll
        for (int ks = 0; ks < 16; ++ks) {
            bf16x8 v;
            #pragma unroll
            for (int j = 0; j < 8; ++j)
                v[j] = (short)f2bf(Us[g4][(ks * 32 + q * 8 + j) * H_ + base + m]);
            UF[g4][ks] = v;
        }
        #pragma unroll
        for (int ks = 0; ks < 8; ++ks) {
            bf16x8 v;
            #pragma unroll
            for (int j = 0; j < 8; ++j)
                v[j] = (short)f2bf(Ws[g4][(ks * 32 + q * 8 + j) * H_ + base + m]);
            WF[g4][ks] = v;
        }
    }

    const float wfc_m = Wfc[base + m];
    float cst[4] = {0.f, 0.f, 0.f, 0.f};   // c-state, C-layout: row q*4+j, col base+m

    unsigned int* flagsG = flags + g * 32;

    // ---- x(0) prefetch: A-frag rows = batch row g*16+m, k = ks*32+q*8+j ----
    float4 xr[16];
    #pragma unroll
    for (int ks = 0; ks < 8; ++ks) {
        const float* xp = X + ((size_t)(g * 16 + m) * S_ + 0) * D_ + ks * 32 + q * 8;
        xr[2 * ks]     = *(const float4*)xp;
        xr[2 * ks + 1] = *(const float4*)(xp + 4);
    }

    for (int t = 0; t < S_; ++t) {
        // ---- x-GEMM (independent of h(t)) — off the exchange critical path ----
        f32x4 acc[4];
        #pragma unroll
        for (int g4 = 0; g4 < 4; ++g4)
            acc[g4] = (f32x4){bias[g4], bias[g4], bias[g4], bias[g4]};
        #pragma unroll
        for (int ks = 0; ks < 8; ++ks) {
            bf16x8 a;
            a[0] = (short)f2bf(xr[2 * ks].x);     a[1] = (short)f2bf(xr[2 * ks].y);
            a[2] = (short)f2bf(xr[2 * ks].z);     a[3] = (short)f2bf(xr[2 * ks].w);
            a[4] = (short)f2bf(xr[2 * ks + 1].x); a[5] = (short)f2bf(xr[2 * ks + 1].y);
            a[6] = (short)f2bf(xr[2 * ks + 1].z); a[7] = (short)f2bf(xr[2 * ks + 1].w);
            #pragma unroll
            for (int g4 = 0; g4 < 4; ++g4)
                acc[g4] = __builtin_amdgcn_mfma_f32_16x16x32_bf16(a, WF[g4][ks], acc[g4], 0, 0, 0);
        }

        // ---- poll: all 32 producers of this group posted h(t) ----
        if (t > 0) {
            const unsigned int tgt = (unsigned int)t;
            for (;;) {
                unsigned int f = __hip_atomic_load(&flagsG[lane & 31],
                                                   __ATOMIC_RELAXED, __HIP_MEMORY_SCOPE_AGENT);
                if (__ballot(f >= tgt) == ~0ull) break;
                __builtin_amdgcn_s_sleep(1);
            }
        }

        // ---- h A-frag loads straight from L3 (sc0 sc1), 16 x 16B per lane ----
        const ushort_t* hrow = hbufS + ((size_t)((t % 3) * B_ + g * 16 + m) * H_ + q * 8);
        uint4v hf[16];
        asm volatile(
            "global_load_dwordx4 %0,  %16, off offset:0   sc0 sc1\n\t"
            "global_load_dwordx4 %1,  %16, off offset:64  sc0 sc1\n\t"
            "global_load_dwordx4 %2,  %16, off offset:128 sc0 sc1\n\t"
            "global_load_dwordx4 %3,  %16, off offset:192 sc0 sc1\n\t"
            "global_load_dwordx4 %4,  %16, off offset:256 sc0 sc1\n\t"
            "global_load_dwordx4 %5,  %16, off offset:320 sc0 sc1\n\t"
            "global_load_dwordx4 %6,  %16, off offset:384 sc0 sc1\n\t"
            "global_load_dwordx4 %7,  %16, off offset:448 sc0 sc1\n\t"
            "global_load_dwordx4 %8,  %16, off offset:512 sc0 sc1\n\t"
            "global_load_dwordx4 %9,  %16, off offset:576 sc0 sc1\n\t"
            "global_load_dwordx4 %10, %16, off offset:640 sc0 sc1\n\t"
            "global_load_dwordx4 %11, %16, off offset:704 sc0 sc1\n\t"
            "global_load_dwordx4 %12, %16, off offset:768 sc0 sc1\n\t"
            "global_load_dwordx4 %13, %16, off offset:832 sc0 sc1\n\t"
            "global_load_dwordx4 %14, %16, off offset:896 sc0 sc1\n\t"
            "global_load_dwordx4 %15, %16, off offset:960 sc0 sc1\n\t"
            "s_waitcnt vmcnt(0)"
            : "=v"(hf[0]), "=v"(hf[1]), "=v"(hf[2]), "=v"(hf[3]),
              "=v"(hf[4]), "=v"(hf[5]), "=v"(hf[6]), "=v"(hf[7]),
              "=v"(hf[8]), "=v"(hf[9]), "=v"(hf[10]), "=v"(hf[11]),
              "=v"(hf[12]), "=v"(hf[13]), "=v"(hf[14]), "=v"(hf[15])
            : "v"(hrow) : "memory");

        // ---- h.U MFMAs: K = 512 ----
        #pragma unroll
        for (int ks = 0; ks < 16; ++ks) {
            bf16x8 a;
            __builtin_memcpy(&a, &hf[ks], 16);
            #pragma unroll
            for (int g4 = 0; g4 < 4; ++g4)
                acc[g4] = __builtin_amdgcn_mfma_f32_16x16x32_bf16(a, UF[g4][ks], acc[g4], 0, 0, 0);
        }

        // ---- activations + state update, fully in-register (C-layout) ----
        float hj[4];
        #pragma unroll
        for (int j = 0; j < 4; ++j) {
            float fv = sigmoid_f(acc[0][j]);
            float iv = sigmoid_f(acc[1][j]);
            float ov = sigmoid_f(acc[2][j]);
            float ch = tanh_f(acc[3][j]);
            cst[j] = fv * cst[j] + iv * ch;
            hj[j]  = ov * tanh_f(cst[j]);
        }

        if (t < S_ - 1) {
            // ---- h(t+1) write-through: 4 ushort stores (16-col segments per row) ----
            ushort_t* hsb = hbufS + ((size_t)(((t + 1) % 3) * B_ + g * 16 + q * 4) * H_ + base + m);
            unsigned int h0 = f2bf(hj[0]), h1 = f2bf(hj[1]), h2 = f2bf(hj[2]), h3 = f2bf(hj[3]);
            asm volatile(
                "global_store_short %0, %1, off offset:0    sc0 sc1\n\t"
                "global_store_short %0, %2, off offset:1024 sc0 sc1\n\t"
                "global_store_short %0, %3, off offset:2048 sc0 sc1\n\t"
                "global_store_short %0, %4, off offset:3072 sc0 sc1"
                :: "v"(hsb), "v"(h0), "v"(h1), "v"(h2), "v"(h3) : "memory");

            // ---- per-wave flag release: drain our stores (all at L3), then post ----
            if (lane == 0) {
                asm volatile(
                    "s_waitcnt vmcnt(0)\n\t"
                    "global_store_dword %0, %1, off sc0 sc1"
                    :: "v"(&flagsG[p]), "v"((unsigned int)(t + 1)) : "memory");
            }
        } else {
            // final state outputs (fp32, pre-rounding)
            #pragma unroll
            for (int j = 0; j < 4; ++j) {
                outH[(size_t)(g * 16 + q * 4 + j) * H_ + base + m] = hj[j];
                outC[(size_t)(g * 16 + q * 4 + j) * H_ + base + m] = cst[j];
            }
        }

        // ---- pred head partials (after release — acks drain at NEXT release) ----
        float pv[4];
        #pragma unroll
        for (int j = 0; j < 4; ++j) pv[j] = hj[j] * wfc_m;
        #pragma unroll
        for (int j = 0; j < 4; ++j) {
            pv[j] += __shfl_xor(pv[j], 1);
            pv[j] += __shfl_xor(pv[j], 2);
            pv[j] += __shfl_xor(pv[j], 4);
            pv[j] += __shfl_xor(pv[j], 8);
        }
        if (m == 0) {
            #pragma unroll
            for (int j = 0; j < 4; ++j)
                atomicAdd(&pred[(size_t)(g * 16 + q * 4 + j) * S_ + t], pv[j]);
        }

        // ---- x(t+1) prefetch (cached loads; consumed at next step's top) ----
        if (t < S_ - 1) {
            #pragma unroll
            for (int ks = 0; ks < 8; ++ks) {
                const float* xp = X + ((size_t)(g * 16 + m) * S_ + (t + 1)) * D_ + ks * 32 + q * 8;
                xr[2 * ks]     = *(const float4*)xp;
                xr[2 * ks + 1] = *(const float4*)(xp + 4);
            }
        }
    }
}

__global__ void pred_fin(const float* __restrict__ pred,
                         const float* __restrict__ bfc,
                         float* __restrict__ out)
{
    int i = blockIdx.x * blockDim.x + threadIdx.x;
    if (i < B_ * S_) out[i] = pred[i] + bfc[0];
}

extern "C" void kernel_launch(void* const* d_in, const int* in_sizes, int n_in,
                              void* d_out, int out_size, void* d_ws, size_t ws_size,
                              hipStream_t stream) {
    const float* X   = (const float*)d_in[0];
    const float* Wf  = (const float*)d_in[1];
    const float* Wi  = (const float*)d_in[2];
    const float* Wo  = (const float*)d_in[3];
    const float* Wc  = (const float*)d_in[4];
    const float* bfp = (const float*)d_in[5];
    const float* bip = (const float*)d_in[6];
    const float* bop = (const float*)d_in[7];
    const float* bcp = (const float*)d_in[8];
    const float* Uf  = (const float*)d_in[9];
    const float* Ui  = (const float*)d_in[10];
    const float* Uo  = (const float*)d_in[11];
    const float* Uc  = (const float*)d_in[12];
    const float* Wfc = (const float*)d_in[13];
    const float* bfc = (const float*)d_in[14];

    // ws layout: pred fp32 [64][512] @0 (128KB) | hbuf bf16 [3][64][512] @131072 (192KB)
    //            | flags @327680 (4 groups x 32 dwords = 512B)
    float*        pred  = (float*)d_ws;
    ushort_t*     hbufS = (ushort_t*)((char*)d_ws + 131072);
    unsigned int* flags = (unsigned int*)((char*)d_ws + 131072 + 196608);

    hipMemsetAsync(d_ws, 0, 131072 + 196608 + 1024, stream);   // zero pred, hbuf, flags

    float* out = (float*)d_out;
    lstm_rec<<<128, 64, 0, stream>>>(X, Wf, Wi, Wo, Wc, bfp, bip, bop, bcp,
                                     Uf, Ui, Uo, Uc, Wfc,
                                     pred, hbufS, flags,
                                     out + 32768, out + 65536);
    pred_fin<<<128, 256, 0, stream>>>(pred, bfc, out);
}

// Round 7
// 2425.234 us; speedup vs baseline: 1.3564x; 1.3564x over previous
//
#include <hip/hip_runtime.h>
#include <hip/hip_bf16.h>

#define B_ 64
#define S_ 512
#define D_ 256
#define H_ 512

typedef __attribute__((ext_vector_type(8))) short bf16x8;
typedef __attribute__((ext_vector_type(4))) float f32x4;
typedef __attribute__((ext_vector_type(4))) unsigned int uint4v;
typedef unsigned short ushort_t;

__device__ __forceinline__ ushort_t f2bf(float f) {
    __hip_bfloat16 h = __float2bfloat16(f);   // RNE rounding
    return *reinterpret_cast<ushort_t*>(&h);
}
__device__ __forceinline__ float sigmoid_f(float x) { return 1.f / (1.f + __expf(-x)); }
__device__ __forceinline__ float tanh_f(float x) { return 1.f - 2.f / (__expf(2.f * x) + 1.f); }

// Block barrier WITHOUT the vmcnt(0) drain __syncthreads imposes: LDS ops are
// ordered (lgkmcnt), but global loads in flight stay in flight.
__device__ __forceinline__ void lds_barrier() {
    asm volatile("s_waitcnt lgkmcnt(0)\n\ts_barrier" ::: "memory");
}

// grid: 32 blocks x 512 threads.
// group g = blockIdx&3 (batch rows g*16..+15), slice s = blockIdx>>2 (h-cols s*64..+63)
// wave w: gate = w>>1, half = w&1 -> two 16-col n-tiles. Weight B-frags persistent
// in VGPRs (fp32->bf16 RNE once).
// Sync: per-WAVE flags (64 per group). Each wave: h-stores (write-through sc0 sc1,
// rows {2w,2w+1} x 64 cols) -> own vmcnt(0) drain -> own flag. Consumers poll all
// 64 flags with a lane-parallel relaxed load + ballot. Only two intra-block
// lds_barrier()s per step (post-h-staging, post-gact). Zero __syncthreads in loop.
__global__ __launch_bounds__(512, 2) void lstm_rec(
    const float* __restrict__ X,
    const float* __restrict__ Wf, const float* __restrict__ Wi,
    const float* __restrict__ Wo, const float* __restrict__ Wc,
    const float* __restrict__ bfp, const float* __restrict__ bip,
    const float* __restrict__ bop, const float* __restrict__ bcp,
    const float* __restrict__ Uf, const float* __restrict__ Ui,
    const float* __restrict__ Uo, const float* __restrict__ Uc,
    const float* __restrict__ Wfc,
    float* __restrict__ pred, unsigned int* __restrict__ hbufU,
    unsigned int* __restrict__ flags,
    float* __restrict__ outH, float* __restrict__ outC)
{
    __shared__ ushort_t hS[16 * 520];   // 520-short stride: 16B-aligned rows
    __shared__ ushort_t xS[16 * 264];
    __shared__ float gact[4][16][68];

    const int tid  = threadIdx.x;
    const int w    = tid >> 6;
    const int lane = tid & 63;
    const int q    = lane >> 4;      // MFMA quad
    const int m    = lane & 15;      // A-row / B-col lane index
    const int gate = w >> 1;
    const int half = w & 1;
    const int g    = blockIdx.x & 3;
    const int s    = blockIdx.x >> 2;

    const int ncol0 = s * 64 + half * 32 + m;
    const int ncol1 = ncol0 + 16;

    const float* Ug = (gate == 0) ? Uf : (gate == 1) ? Ui : (gate == 2) ? Uo : Uc;
    const float* Wg = (gate == 0) ? Wf : (gate == 1) ? Wi : (gate == 2) ? Wo : Wc;
    const float* bg = (gate == 0) ? bfp : (gate == 1) ? bip : (gate == 2) ? bop : bcp;

    const float bias0 = bg[ncol0];
    const float bias1 = bg[ncol1];

    // ---- one-time: B-fragments into registers (fp32 -> bf16 RNE) ----
    bf16x8 UF[2][16];
    bf16x8 WF[2][8];
    #pragma unroll
    for (int tt = 0; tt < 2; ++tt) {
        const int nc = tt ? ncol1 : ncol0;
        #pragma unroll
        for (int ks = 0; ks < 16; ++ks) {
            bf16x8 v;
            #pragma unroll
            for (int j = 0; j < 8; ++j)
                v[j] = (short)f2bf(Ug[(ks * 32 + q * 8 + j) * H_ + nc]);
            UF[tt][ks] = v;
        }
        #pragma unroll
        for (int ks = 0; ks < 8; ++ks) {
            bf16x8 v;
            #pragma unroll
            for (int j = 0; j < 8; ++j)
                v[j] = (short)f2bf(Wg[(ks * 32 + q * 8 + j) * H_ + nc]);
            WF[tt][ks] = v;
        }
    }

    const int urow  = tid >> 5;   // update row (batch within group), 0..15; wave w -> rows {2w,2w+1}
    const int upair = tid & 31;   // update col-pair: owns cols 2*upair, 2*upair+1
    const float2 wfc2 = *(const float2*)&Wfc[s * 64 + 2 * upair];

    float cr0 = 0.f, cr1 = 0.f;   // c-state in registers (thread-exclusive)

    unsigned int* flagsG = flags + g * 64;   // 64 per-wave flags for this group
    const int myflag = s * 8 + w;            // this wave's flag index

    // ---- preamble: stage x(0) into LDS (ordered by first lds_barrier) ----
    {
        const float* xsrc = &X[((size_t)(g * 16 + urow) * S_ + 0) * D_ + upair * 8];
        float4 a = *(const float4*)xsrc;
        float4 b = *(const float4*)(xsrc + 4);
        bf16x8 v;
        v[0] = (short)f2bf(a.x); v[1] = (short)f2bf(a.y);
        v[2] = (short)f2bf(a.z); v[3] = (short)f2bf(a.w);
        v[4] = (short)f2bf(b.x); v[5] = (short)f2bf(b.y);
        v[6] = (short)f2bf(b.z); v[7] = (short)f2bf(b.w);
        *(bf16x8*)&xS[urow * 264 + upair * 8] = v;
    }

    float4 xr0, xr1;   // x(t+1) prefetch registers

    for (int t = 0; t < S_; ++t) {
        // ---- A: per-wave poll — all 64 waves of this group posted h(t) ----
        if (t > 0) {
            const unsigned int tgt = (unsigned int)t;
            for (;;) {
                unsigned int f = __hip_atomic_load(&flagsG[lane],
                                                   __ATOMIC_RELAXED, __HIP_MEMORY_SCOPE_AGENT);
                if (__ballot(f >= tgt) == ~0ull) break;
                __builtin_amdgcn_s_sleep(1);
            }
        }

        // ---- C: stage h(t) [16x512] from L3 into LDS (sc0 sc1 dwordx4 pair) ----
        {
            const int row  = tid >> 5;
            const int dcol = (tid & 31) * 8;
            const unsigned int* p0 = &hbufU[(size_t)((t % 3) * B_ + g * 16 + row) * 256 + dcol];
            const unsigned int* p1 = p0 + 4;
            uint4v ra, rb;
            asm volatile(
                "global_load_dwordx4 %0, %2, off sc0 sc1\n\t"
                "global_load_dwordx4 %1, %3, off sc0 sc1\n\t"
                "s_waitcnt vmcnt(0)"
                : "=v"(ra), "=v"(rb) : "v"(p0), "v"(p1) : "memory");
            *(uint4v*)&hS[row * 520 + dcol * 2]     = ra;
            *(uint4v*)&hS[row * 520 + dcol * 2 + 8] = rb;
        }
        lds_barrier();   // D — no vmem pending, cheap

        // ---- E: issue x(t+1) loads (stay in flight across F), gate GEMMs, acts ----
        if (t + 1 < S_) {
            const float* xsrc = &X[((size_t)(g * 16 + urow) * S_ + (t + 1)) * D_ + upair * 8];
            xr0 = *(const float4*)xsrc;
            xr1 = *(const float4*)(xsrc + 4);
        }
        f32x4 accA0 = {bias0, bias0, bias0, bias0};
        f32x4 accA1 = {bias1, bias1, bias1, bias1};
        f32x4 accB0 = {0.f, 0.f, 0.f, 0.f};
        f32x4 accB1 = {0.f, 0.f, 0.f, 0.f};
        #pragma unroll
        for (int ks = 0; ks < 8; ++ks) {
            bf16x8 a = *(const bf16x8*)&xS[m * 264 + ks * 32 + q * 8];
            accA0 = __builtin_amdgcn_mfma_f32_16x16x32_bf16(a, WF[0][ks], accA0, 0, 0, 0);
            accA1 = __builtin_amdgcn_mfma_f32_16x16x32_bf16(a, WF[1][ks], accA1, 0, 0, 0);
        }
        #pragma unroll
        for (int ks = 0; ks < 16; ++ks) {
            bf16x8 a = *(const bf16x8*)&hS[m * 520 + ks * 32 + q * 8];
            accB0 = __builtin_amdgcn_mfma_f32_16x16x32_bf16(a, UF[0][ks], accB0, 0, 0, 0);
            accB1 = __builtin_amdgcn_mfma_f32_16x16x32_bf16(a, UF[1][ks], accB1, 0, 0, 0);
        }
        #pragma unroll
        for (int j = 0; j < 4; ++j) {
            float v0 = accA0[j] + accB0[j];
            float v1 = accA1[j] + accB1[j];
            v0 = (gate < 3) ? sigmoid_f(v0) : tanh_f(v0);
            v1 = (gate < 3) ? sigmoid_f(v1) : tanh_f(v1);
            gact[gate][q * 4 + j][half * 32 + m]      = v0;
            gact[gate][q * 4 + j][half * 32 + 16 + m] = v1;
        }
        lds_barrier();   // F — lgkm only; x loads remain in flight

        // ---- G: update own 2 cells, h write-through, own drain, own flag ----
        float2 f2v = *(const float2*)&gact[0][urow][2 * upair];
        float2 i2v = *(const float2*)&gact[1][urow][2 * upair];
        float2 o2v = *(const float2*)&gact[2][urow][2 * upair];
        float2 ch2 = *(const float2*)&gact[3][urow][2 * upair];
        cr0 = f2v.x * cr0 + i2v.x * ch2.x;
        cr1 = f2v.y * cr1 + i2v.y * ch2.y;
        float hv0 = o2v.x * tanh_f(cr0);
        float hv1 = o2v.y * tanh_f(cr1);

        float pv = hv0 * wfc2.x + hv1 * wfc2.y;

        if (t < S_ - 1) {
            unsigned int packed = (unsigned int)f2bf(hv0) | ((unsigned int)f2bf(hv1) << 16);
            __hip_atomic_store(
                &hbufU[(size_t)(((t + 1) % 3) * B_ + g * 16 + urow) * 256 + s * 32 + upair],
                packed, __ATOMIC_RELAXED, __HIP_MEMORY_SCOPE_AGENT);
            // drain THIS wave's stores (h at L3; also x residual), then post own flag
            asm volatile("s_waitcnt vmcnt(0)" ::: "memory");
            if (lane == 0) {
                __hip_atomic_store(&flagsG[myflag], (unsigned int)(t + 1),
                                   __ATOMIC_RELAXED, __HIP_MEMORY_SCOPE_AGENT);
            }
            // stage x(t+1) (xr guaranteed resident after the drain)
            bf16x8 v;
            v[0] = (short)f2bf(xr0.x); v[1] = (short)f2bf(xr0.y);
            v[2] = (short)f2bf(xr0.z); v[3] = (short)f2bf(xr0.w);
            v[4] = (short)f2bf(xr1.x); v[5] = (short)f2bf(xr1.y);
            v[6] = (short)f2bf(xr1.z); v[7] = (short)f2bf(xr1.w);
            *(bf16x8*)&xS[urow * 264 + upair * 8] = v;
        } else {
            *(float2*)&outH[(g * 16 + urow) * H_ + s * 64 + 2 * upair] = make_float2(hv0, hv1);
            *(float2*)&outC[(g * 16 + urow) * H_ + s * 64 + 2 * upair] = make_float2(cr0, cr1);
        }

        // ---- pred head (after flag release — off the inter-block critical path) ----
        pv += __shfl_xor(pv, 16);
        pv += __shfl_xor(pv, 8);
        pv += __shfl_xor(pv, 4);
        pv += __shfl_xor(pv, 2);
        pv += __shfl_xor(pv, 1);
        if (upair == 0) atomicAdd(&pred[(g * 16 + urow) * S_ + t], pv);
    }
}

__global__ void pred_fin(const float* __restrict__ pred,
                         const float* __restrict__ bfc,
                         float* __restrict__ out)
{
    int i = blockIdx.x * blockDim.x + threadIdx.x;
    if (i < B_ * S_) out[i] = pred[i] + bfc[0];
}

extern "C" void kernel_launch(void* const* d_in, const int* in_sizes, int n_in,
                              void* d_out, int out_size, void* d_ws, size_t ws_size,
                              hipStream_t stream) {
    const float* X   = (const float*)d_in[0];
    const float* Wf  = (const float*)d_in[1];
    const float* Wi  = (const float*)d_in[2];
    const float* Wo  = (const float*)d_in[3];
    const float* Wc  = (const float*)d_in[4];
    const float* bfp = (const float*)d_in[5];
    const float* bip = (const float*)d_in[6];
    const float* bop = (const float*)d_in[7];
    const float* bcp = (const float*)d_in[8];
    const float* Uf  = (const float*)d_in[9];
    const float* Ui  = (const float*)d_in[10];
    const float* Uo  = (const float*)d_in[11];
    const float* Uc  = (const float*)d_in[12];
    const float* Wfc = (const float*)d_in[13];
    const float* bfc = (const float*)d_in[14];

    // ws layout: pred fp32 [64][512] @0 (128KB) | hbuf bf16 [3][64][512] @131072 (192KB)
    //            | flags @327680 (4 groups x 64 dwords = 1KB)
    float*        pred  = (float*)d_ws;
    unsigned int* hbufU = (unsigned int*)((char*)d_ws + 131072);
    unsigned int* flags = (unsigned int*)((char*)d_ws + 131072 + 196608);

    hipMemsetAsync(d_ws, 0, 131072 + 196608 + 2048, stream);   // zero pred, hbuf, flags

    float* out = (float*)d_out;
    lstm_rec<<<32, 512, 0, stream>>>(X, Wf, Wi, Wo, Wc, bfp, bip, bop, bcp,
                                     Uf, Ui, Uo, Uc, Wfc,
                                     pred, hbufU, flags,
                                     out + 32768, out + 65536);
    pred_fin<<<128, 256, 0, stream>>>(pred, bfc, out);
}